// Round 2
// baseline (310.246 us; speedup 1.0000x reference)
//
#include <hip/hip_runtime.h>

typedef float f32x4 __attribute__((ext_vector_type(4)));
typedef short s16x8 __attribute__((ext_vector_type(8)));

#define DEV __device__ __forceinline__

DEV short f2bf(float f) {
    union { float f; unsigned u; } v; v.f = f;
    unsigned r = v.u + 0x7fffu + ((v.u >> 16) & 1u);
    return (short)(r >> 16);
}

// ---------------------------------------------------------------- constants
// B=2, Q=K=2048, D=512, H=8, hd=64. KV padded: 2048 real + 1 zero-attn + 31 pad = 2080
#define SEQ   2048
#define DMODEL 512
#define KPAD  2080
#define KROWS 4224   /* 2*2080 rounded up to multiple of 128 */

// ws offsets (bytes)
#define OFF_QN   0ull
#define OFF_KN   4194304ull
#define OFF_VN   8519680ull
#define OFF_QH   12845056ull
#define OFF_KH   17039360ull
#define OFF_VH   21364736ull
#define OFF_VHT  25690112ull
#define OFF_AV   29949952ull
#define OFF_WQT  34144256ull
#define OFF_WKT  34668544ull
#define OFF_WVT  35192832ull
#define OFF_WOT  35717120ull
#define OFF_GWT  36241408ull
#define WS_NEEDED 37289984ull
// aliased (lifetimes disjoint):
#define OFF_AP   0ull          /* attn_proj f32 (8 MB) over qn+kn */
#define OFF_CC   8519680ull    /* concat bf16 (8 MB) over vn+qh   */
#define OFF_GL   17039360ull   /* gate logits f32 (8 MB) over kh+vh */

// ---------------------------------------------------------------- LayerNorm + cast
// one wave per row of 512; rows beyond B*Spad -> 0; row j==Sreal -> beta (LN of zero row)
__global__ __launch_bounds__(256) void ln_kernel(
    const float* __restrict__ in, const float* __restrict__ gamma,
    const float* __restrict__ beta, short* __restrict__ out,
    int Sreal, int Spad, int B)
{
    int w = threadIdx.x >> 6, l = threadIdx.x & 63;
    int r = blockIdx.x * 4 + w;
    short* op = out + (size_t)r * DMODEL + l * 8;
    s16x8 o = {0,0,0,0,0,0,0,0};
    if (r >= B * Spad) { *(s16x8*)op = o; return; }
    int b = r / Spad, j = r - b * Spad;
    if (j >= Sreal) {
        if (j == Sreal) {
            f32x4 b0 = *(const f32x4*)(beta + l*8);
            f32x4 b1 = *(const f32x4*)(beta + l*8 + 4);
            #pragma unroll
            for (int t=0;t<4;t++){ o[t]=f2bf(b0[t]); o[t+4]=f2bf(b1[t]); }
        }
        *(s16x8*)op = o; return;
    }
    const float* ip = in + ((size_t)b * Sreal + j) * DMODEL + l * 8;
    f32x4 x0 = *(const f32x4*)ip;
    f32x4 x1 = *(const f32x4*)(ip + 4);
    float s = x0[0]+x0[1]+x0[2]+x0[3]+x1[0]+x1[1]+x1[2]+x1[3];
    #pragma unroll
    for (int off=1; off<64; off<<=1) s += __shfl_xor(s, off);
    float mean = s * (1.0f/512.0f);
    float vs = 0.f;
    #pragma unroll
    for (int t=0;t<4;t++){ float d0=x0[t]-mean, d1=x1[t]-mean; vs += d0*d0 + d1*d1; }
    #pragma unroll
    for (int off=1; off<64; off<<=1) vs += __shfl_xor(vs, off);
    float rstd = rsqrtf(vs * (1.0f/512.0f) + 1e-5f);
    f32x4 g0 = *(const f32x4*)(gamma + l*8), g1 = *(const f32x4*)(gamma + l*8 + 4);
    f32x4 b0 = *(const f32x4*)(beta + l*8),  b1 = *(const f32x4*)(beta + l*8 + 4);
    #pragma unroll
    for (int t=0;t<4;t++){
        o[t]   = f2bf((x0[t]-mean)*rstd*g0[t] + b0[t]);
        o[t+4] = f2bf((x1[t]-mean)*rstd*g1[t] + b1[t]);
    }
    *(s16x8*)op = o;
}

// ---------------------------------------------------------------- weight transpose+cast
// out[n*K + k] = bf16(in[k*N + n])
__global__ __launch_bounds__(256) void wt_cast(
    const float* __restrict__ in, short* __restrict__ out, int K, int N)
{
    int idx = blockIdx.x * 256 + threadIdx.x;
    int n = idx / K, k = idx - n * K;
    out[idx] = f2bf(in[(size_t)k * N + n]);
}

// ---------------------------------------------------------------- bf16 GEMM  C = A @ Bt^T
// A (M,K) bf16 row-major, Bt (N,K) bf16 row-major. 128x128 tile, BK=64, 4 waves.
// global_load_lds w/ pre-swizzled global source (slot ^= row&7), swizzled ds_read_b128.
template<bool BF16OUT, bool BIAS>
__global__ __launch_bounds__(256) void gemm_bt(
    const short* __restrict__ A, const short* __restrict__ Bt,
    void* __restrict__ Cv, const float* __restrict__ bias,
    int M, int N, int K)
{
    __shared__ short As[128*64];
    __shared__ short Bs[128*64];
    int tid = threadIdx.x;
    int w = tid >> 6, l = tid & 63;
    int lr = l & 15, lg = l >> 4;
    int nt = N >> 7;
    int tm = blockIdx.x / nt, tn = blockIdx.x - tm * nt;
    int wm = w >> 1, wn = w & 1;
    int srow = tid >> 3, sslot = tid & 7;

    f32x4 acc[4][4];
    #pragma unroll
    for (int m=0;m<4;m++)
        #pragma unroll
        for (int n=0;n<4;n++) acc[m][n] = (f32x4){0.f,0.f,0.f,0.f};

    for (int k0 = 0; k0 < K; k0 += 64) {
        #pragma unroll
        for (int i=0;i<4;i++){
            int row = i*32 + srow;
            int gslot = sslot ^ (row & 7);
            const short* ga = A  + (size_t)(tm*128 + row) * K + k0 + gslot*8;
            const short* gb = Bt + (size_t)(tn*128 + row) * K + k0 + gslot*8;
            short* la = As + (i*32 + w*8) * 64;
            short* lb = Bs + (i*32 + w*8) * 64;
            __builtin_amdgcn_global_load_lds((const __attribute__((address_space(1))) void*)ga,
                                             (__attribute__((address_space(3))) void*)la, 16, 0, 0);
            __builtin_amdgcn_global_load_lds((const __attribute__((address_space(1))) void*)gb,
                                             (__attribute__((address_space(3))) void*)lb, 16, 0, 0);
        }
        __syncthreads();
        #pragma unroll
        for (int s=0;s<2;s++){
            s16x8 af[4], bfr[4];
            #pragma unroll
            for (int m=0;m<4;m++){
                int row = wm*64 + m*16 + lr;
                int slot = (s*4 + lg) ^ (row & 7);
                af[m] = *(const s16x8*)(As + row*64 + slot*8);
            }
            #pragma unroll
            for (int n=0;n<4;n++){
                int row = wn*64 + n*16 + lr;
                int slot = (s*4 + lg) ^ (row & 7);
                bfr[n] = *(const s16x8*)(Bs + row*64 + slot*8);
            }
            #pragma unroll
            for (int m=0;m<4;m++)
                #pragma unroll
                for (int n=0;n<4;n++)
                    acc[m][n] = __builtin_amdgcn_mfma_f32_16x16x32_bf16(af[m], bfr[n], acc[m][n], 0, 0, 0);
        }
        __syncthreads();
    }

    int rb = tm*128 + wm*64;
    int cbase = tn*128 + wn*64;
    #pragma unroll
    for (int n=0;n<4;n++){
        int col = cbase + n*16 + lr;
        float badd = BIAS ? bias[col] : 0.0f;
        #pragma unroll
        for (int m=0;m<4;m++){
            #pragma unroll
            for (int j=0;j<4;j++){
                int row = rb + m*16 + lg*4 + j;
                if (row < M){
                    float v = acc[m][n][j] + badd;
                    if (BF16OUT) ((short*)Cv)[(size_t)row*N + col] = f2bf(v);
                    else         ((float*)Cv)[(size_t)row*N + col] = v;
                }
            }
        }
    }
}

// ---------------------------------------------------------------- vh -> vhT[b][h][64][KPAD]
__global__ __launch_bounds__(256) void transpose_v(
    const short* __restrict__ vh, short* __restrict__ vhT)
{
    __shared__ short t[64][72];   // 72*2=144 bytes/row: 16B-aligned, bank-spread
    int tid = threadIdx.x, bid = blockIdx.x;
    int kt = bid % 33; int hh = (bid / 33) & 7; int b = bid / (33*8);
    int k0 = kt * 64;
    int rr = tid >> 3, c8 = (tid & 7) * 8;
    #pragma unroll
    for (int p=0;p<2;p++){
        int kr = p*32 + rr;
        int gk = k0 + kr;
        s16x8 v = {0,0,0,0,0,0,0,0};
        if (gk < KPAD) v = *(const s16x8*)(vh + (size_t)(b*KPAD + gk)*DMODEL + hh*64 + c8);
        *(s16x8*)&t[kr][c8] = v;
    }
    __syncthreads();
    #pragma unroll
    for (int p=0;p<2;p++){
        int dr = p*32 + rr;
        if (k0 + c8 < KPAD){
            s16x8 o;
            #pragma unroll
            for (int j2=0;j2<8;j2++) o[j2] = t[c8+j2][dr];
            *(s16x8*)(vhT + ((size_t)(b*8 + hh)*64 + dr)*KPAD + k0 + c8) = o;
        }
    }
}

// ---------------------------------------------------------------- flash attention
// 1 wave per (b, h, 16-row q-tile). Online softmax over 65 chunks of 32 keys.
__global__ __launch_bounds__(256) void flash_kernel(
    const short* __restrict__ qh, const short* __restrict__ kh,
    const short* __restrict__ vhT, const int* __restrict__ kmask,
    const int* __restrict__ qmask, short* __restrict__ av)
{
    __shared__ short plds[4][640];   // per-wave 16x32 P tile, row stride 40
    int tid = threadIdx.x;
    int w = tid >> 6, l = tid & 63;
    int wid = blockIdx.x * 4 + w;
    int b = wid >> 10;
    int h = (wid >> 7) & 7;
    int q0 = (wid & 127) << 4;
    int cl = l & 15, rg = l >> 4;

    const short* qp = qh + ((size_t)(b*SEQ + q0 + cl))*DMODEL + h*64 + rg*8;
    s16x8 qf0 = *(const s16x8*)qp;
    s16x8 qf1 = *(const s16x8*)(qp + 32);

    f32x4 O[4];
    float mrow[4], lsum[4];
    #pragma unroll
    for (int n=0;n<4;n++) O[n] = (f32x4){0.f,0.f,0.f,0.f};
    #pragma unroll
    for (int j=0;j<4;j++){ mrow[j] = -1e30f; lsum[j] = 0.f; }

    const short* khb = kh + (size_t)b*KPAD*DMODEL + h*64;
    const short* vtb = vhT + (size_t)(b*8 + h)*64*KPAD;
    const int* kmb = kmask + b*SEQ;
    short* pl = plds[w];

    for (int kc = 0; kc < 65; ++kc) {
        int k0 = kc * 32;
        f32x4 sf[2];
        #pragma unroll
        for (int nh=0; nh<2; ++nh) {
            const short* kp = khb + (size_t)(k0 + nh*16 + cl)*DMODEL + rg*8;
            s16x8 ka = *(const s16x8*)kp;
            s16x8 kb2 = *(const s16x8*)(kp + 32);
            f32x4 z = (f32x4){0.f,0.f,0.f,0.f};
            z = __builtin_amdgcn_mfma_f32_16x16x32_bf16(qf0, ka,  z, 0, 0, 0);
            z = __builtin_amdgcn_mfma_f32_16x16x32_bf16(qf1, kb2, z, 0, 0, 0);
            sf[nh] = z;
        }
        float sv[2][4];
        #pragma unroll
        for (int nh=0; nh<2; ++nh){
            int jk = k0 + nh*16 + cl;
            int mk = (jk < SEQ) ? kmb[jk] : (jk == SEQ ? 1 : 0);
            #pragma unroll
            for (int j=0;j<4;j++) sv[nh][j] = mk ? sf[nh][j]*0.125f : -1e30f;
        }
        float ml[4];
        #pragma unroll
        for (int j=0;j<4;j++) ml[j] = fmaxf(sv[0][j], sv[1][j]);
        #pragma unroll
        for (int off=1; off<16; off<<=1){
            #pragma unroll
            for (int j=0;j<4;j++) ml[j] = fmaxf(ml[j], __shfl_xor(ml[j], off));
        }
        float pr[2][4], ps[4];
        #pragma unroll
        for (int j=0;j<4;j++){
            float mn = fmaxf(mrow[j], ml[j]);
            float sc = __expf(mrow[j] - mn);
            mrow[j] = mn;
            pr[0][j] = __expf(sv[0][j] - mn);
            pr[1][j] = __expf(sv[1][j] - mn);
            ps[j] = pr[0][j] + pr[1][j];
            lsum[j] *= sc;
            #pragma unroll
            for (int n=0;n<4;n++) O[n][j] *= sc;
        }
        #pragma unroll
        for (int off=1; off<16; off<<=1){
            #pragma unroll
            for (int j=0;j<4;j++) ps[j] += __shfl_xor(ps[j], off);
        }
        #pragma unroll
        for (int j=0;j<4;j++) lsum[j] += ps[j];
        // P -> LDS (bf16), then reload as MFMA-A fragment
        #pragma unroll
        for (int nh=0; nh<2; ++nh)
            #pragma unroll
            for (int j=0;j<4;j++)
                pl[(rg*4 + j)*40 + nh*16 + cl] = f2bf(pr[nh][j]);
        s16x8 pa = *(const s16x8*)(pl + cl*40 + rg*8);
        #pragma unroll
        for (int n=0;n<4;n++){
            s16x8 vf = *(const s16x8*)(vtb + (size_t)(n*16 + cl)*KPAD + k0 + rg*8);
            O[n] = __builtin_amdgcn_mfma_f32_16x16x32_bf16(pa, vf, O[n], 0, 0, 0);
        }
    }

    #pragma unroll
    for (int j=0;j<4;j++){
        int row = q0 + rg*4 + j;
        int qm = qmask[b*SEQ + row];
        float inv = qm ? (1.0f / lsum[j]) : 0.0f;
        #pragma unroll
        for (int n=0;n<4;n++){
            av[(size_t)(b*SEQ + row)*DMODEL + h*64 + n*16 + cl] = f2bf(O[n][j] * inv);
        }
    }
}

// ---------------------------------------------------------------- concat(query, attn_proj) -> bf16
__global__ __launch_bounds__(256) void concat_cast(
    const float* __restrict__ q, const float* __restrict__ ap, short* __restrict__ cc)
{
    int idx = blockIdx.x * 256 + threadIdx.x;   // 8 outputs per thread
    int row = idx >> 7;
    int c = (idx & 127) << 3;
    const float* src = (c < DMODEL) ? (q + (size_t)row*DMODEL + c)
                                    : (ap + (size_t)row*DMODEL + (c - DMODEL));
    f32x4 a = *(const f32x4*)src;
    f32x4 b2 = *(const f32x4*)(src + 4);
    s16x8 o;
    #pragma unroll
    for (int t=0;t<4;t++){ o[t] = f2bf(a[t]); o[t+4] = f2bf(b2[t]); }
    *(s16x8*)(cc + (size_t)idx*8) = o;
}

// ---------------------------------------------------------------- gated combine
__global__ __launch_bounds__(256) void combine_kernel(
    const float* __restrict__ q, const float* __restrict__ ap,
    const float* __restrict__ gl, float* __restrict__ out)
{
    size_t i = ((size_t)blockIdx.x * 256 + threadIdx.x) * 4;
    f32x4 qv = *(const f32x4*)(q + i);
    f32x4 avv = *(const f32x4*)(ap + i);
    f32x4 gv = *(const f32x4*)(gl + i);
    f32x4 o;
    #pragma unroll
    for (int t=0;t<4;t++){
        float g = 1.0f / (1.0f + __expf(-gv[t]));
        o[t] = qv[t] + g * qv[t] + (1.0f - g) * avv[t];
    }
    *(f32x4*)(out + i) = o;
}

// ---------------------------------------------------------------- launch
extern "C" void kernel_launch(void* const* d_in, const int* in_sizes, int n_in,
                              void* d_out, int out_size, void* d_ws, size_t ws_size,
                              hipStream_t stream)
{
    const float* query = (const float*)d_in[0];
    const float* key   = (const float*)d_in[1];
    const float* value = (const float*)d_in[2];
    const float* Wq    = (const float*)d_in[3];
    const float* Wk    = (const float*)d_in[4];
    const float* Wv    = (const float*)d_in[5];
    const float* Wo    = (const float*)d_in[6];
    const float* gW    = (const float*)d_in[7];
    const float* gB    = (const float*)d_in[8];
    const float* qg    = (const float*)d_in[9];
    const float* qb    = (const float*)d_in[10];
    const float* kg    = (const float*)d_in[11];
    const float* kb    = (const float*)d_in[12];
    const float* vg    = (const float*)d_in[13];
    const float* vb    = (const float*)d_in[14];
    const int* qmask   = (const int*)d_in[15];
    const int* kmask   = (const int*)d_in[16];
    float* out = (float*)d_out;
    char* ws = (char*)d_ws;

    // Defensive: if the harness workspace is smaller than our plan, do nothing
    // rather than scribble OOB (clean wrong-answer instead of a dead container).
    if (ws_size < WS_NEEDED) return;

    short* qn  = (short*)(ws + OFF_QN);
    short* kn  = (short*)(ws + OFF_KN);
    short* vn  = (short*)(ws + OFF_VN);
    short* qh  = (short*)(ws + OFF_QH);
    short* khp = (short*)(ws + OFF_KH);
    short* vhp = (short*)(ws + OFF_VH);
    short* vhT = (short*)(ws + OFF_VHT);
    short* av  = (short*)(ws + OFF_AV);
    short* WqT = (short*)(ws + OFF_WQT);
    short* WkT = (short*)(ws + OFF_WKT);
    short* WvT = (short*)(ws + OFF_WVT);
    short* WoT = (short*)(ws + OFF_WOT);
    short* gWT = (short*)(ws + OFF_GWT);
    float* ap  = (float*)(ws + OFF_AP);
    short* cc  = (short*)(ws + OFF_CC);
    float* gl  = (float*)(ws + OFF_GL);

    // 1. layernorm + cast (K/V padded to 2080 rows/batch: row2048=beta, rest 0)
    ln_kernel<<<1024, 256, 0, stream>>>(query, qg, qb, qn, SEQ, SEQ, 2);
    ln_kernel<<<1056, 256, 0, stream>>>(key,   kg, kb, kn, SEQ, KPAD, 2);
    ln_kernel<<<1056, 256, 0, stream>>>(value, vg, vb, vn, SEQ, KPAD, 2);

    // 2. weights -> bf16 transposed (N,K)
    wt_cast<<<1024, 256, 0, stream>>>(Wq, WqT, 512, 512);
    wt_cast<<<1024, 256, 0, stream>>>(Wk, WkT, 512, 512);
    wt_cast<<<1024, 256, 0, stream>>>(Wv, WvT, 512, 512);
    wt_cast<<<1024, 256, 0, stream>>>(Wo, WoT, 512, 512);
    wt_cast<<<2048, 256, 0, stream>>>(gW, gWT, 1024, 512);

    // 3. projections (bf16 out)
    gemm_bt<true,false><<<128, 256, 0, stream>>>(qn, WqT, qh,  nullptr, 4096, 512, 512);
    gemm_bt<true,false><<<132, 256, 0, stream>>>(kn, WkT, khp, nullptr, KROWS, 512, 512);
    gemm_bt<true,false><<<132, 256, 0, stream>>>(vn, WvT, vhp, nullptr, KROWS, 512, 512);

    // 4. V transpose for PV MFMA B-operand
    transpose_v<<<528, 256, 0, stream>>>(vhp, vhT);

    // 5. flash attention (+ key mask, zero-attn slot, query-mask zeroing)
    flash_kernel<<<512, 256, 0, stream>>>(qh, khp, vhT, kmask, qmask, av);

    // 6. output projection (f32 out)
    gemm_bt<false,false><<<128, 256, 0, stream>>>(av, WoT, ap, nullptr, 4096, 512, 512);

    // 7. concat(original query, attn_proj) -> bf16
    concat_cast<<<2048, 256, 0, stream>>>(query, ap, cc);

    // 8. gate logits = concat @ g_w + g_b (f32 out)
    gemm_bt<false,true><<<128, 256, 0, stream>>>(cc, gWT, gl, gB, 4096, 512, 1024);

    // 9. out = q + sigmoid(gl)*q + (1-sigmoid(gl))*ap
    combine_kernel<<<2048, 256, 0, stream>>>(query, ap, gl, out);

    (void)in_sizes; (void)n_in; (void)out_size;
}

// Round 4
// 287.145 us; speedup vs baseline: 1.0805x; 1.0805x over previous
//
#include <hip/hip_runtime.h>

typedef float f32x4 __attribute__((ext_vector_type(4)));
typedef short s16x8 __attribute__((ext_vector_type(8)));

#define DEV __device__ __forceinline__

DEV short f2bf(float f) {
    union { float f; unsigned u; } v; v.f = f;
    unsigned r = v.u + 0x7fffu + ((v.u >> 16) & 1u);
    return (short)(r >> 16);
}
DEV float bf2f(short s) {
    union { unsigned u; float f; } v; v.u = ((unsigned)(unsigned short)s) << 16;
    return v.f;
}

// B=2, Q=K=2048, D=512, H=8, hd=64. KV padded: 2048 real + 1 zero-attn + 31 pad = 2080
#define SEQ    2048
#define DMODEL 512
#define KPAD   2080
#define NROWS  32768   /* B*H*SEQ flash output rows */

// ws offsets (bytes) — identical envelope to the round-2 layout that passed.
#define OFF_QN   0ull
#define OFF_KN   4194304ull
#define OFF_VN   8519680ull
#define OFF_QH   12845056ull
#define OFF_KH   17039360ull
#define OFF_VH   21364736ull
#define OFF_VHT  25690112ull
#define OFF_AV   29949952ull
#define OFF_WQT  34144256ull
#define OFF_WKT  34668544ull
#define OFF_WVT  35192832ull
#define OFF_WOT  35717120ull
#define OFF_GWT  36241408ull
#define WS_NEEDED 37289984ull
// aliased (lifetimes disjoint):
#define OFF_ON   0ull          /* flash partial O bf16 [2][32768][64] = 8.39 MB, over qn+kn (dead post-proj) */
#define OFF_ML   8388608ull    /* flash partial (m,l) f32 [2][32768][2] = 512 KB, over kn/vn tail */
#define OFF_KB   8912896ull    /* key bias f32 [2][2080] — written AFTER v-proj (vn region) */
#define OFF_AP   17039360ull   /* attn_proj f32 (8.39 MB) over kh+vh (dead post-flash) */

// ---------------------------------------------------------------- LayerNorm + cast
__global__ __launch_bounds__(256) void ln_kernel(
    const float* __restrict__ in, const float* __restrict__ gamma,
    const float* __restrict__ beta, short* __restrict__ out,
    int Sreal, int Spad, int B)
{
    int w = threadIdx.x >> 6, l = threadIdx.x & 63;
    int r = blockIdx.x * 4 + w;
    short* op = out + (size_t)r * DMODEL + l * 8;
    s16x8 o = {0,0,0,0,0,0,0,0};
    if (r >= B * Spad) { *(s16x8*)op = o; return; }
    int b = r / Spad, j = r - b * Spad;
    if (j >= Sreal) {
        if (j == Sreal) {
            f32x4 b0 = *(const f32x4*)(beta + l*8);
            f32x4 b1 = *(const f32x4*)(beta + l*8 + 4);
            #pragma unroll
            for (int t=0;t<4;t++){ o[t]=f2bf(b0[t]); o[t+4]=f2bf(b1[t]); }
        }
        *(s16x8*)op = o; return;
    }
    const float* ip = in + ((size_t)b * Sreal + j) * DMODEL + l * 8;
    f32x4 x0 = *(const f32x4*)ip;
    f32x4 x1 = *(const f32x4*)(ip + 4);
    float s = x0[0]+x0[1]+x0[2]+x0[3]+x1[0]+x1[1]+x1[2]+x1[3];
    #pragma unroll
    for (int off=1; off<64; off<<=1) s += __shfl_xor(s, off);
    float mean = s * (1.0f/512.0f);
    float vs = 0.f;
    #pragma unroll
    for (int t=0;t<4;t++){ float d0=x0[t]-mean, d1=x1[t]-mean; vs += d0*d0 + d1*d1; }
    #pragma unroll
    for (int off=1; off<64; off<<=1) vs += __shfl_xor(vs, off);
    float rstd = rsqrtf(vs * (1.0f/512.0f) + 1e-5f);
    f32x4 g0 = *(const f32x4*)(gamma + l*8), g1 = *(const f32x4*)(gamma + l*8 + 4);
    f32x4 b0 = *(const f32x4*)(beta + l*8),  b1 = *(const f32x4*)(beta + l*8 + 4);
    #pragma unroll
    for (int t=0;t<4;t++){
        o[t]   = f2bf((x0[t]-mean)*rstd*g0[t] + b0[t]);
        o[t+4] = f2bf((x1[t]-mean)*rstd*g1[t] + b1[t]);
    }
    *(s16x8*)op = o;
}

// ---------------------------------------------------------------- coalesced weight transpose+cast
// in (K,N) f32 -> out (N,K) bf16, 32x32 LDS tiles
__global__ __launch_bounds__(256) void wt_cast_t(
    const float* __restrict__ in, short* __restrict__ out, int K, int N)
{
    __shared__ float t[32][33];
    int nt = N >> 5;
    int bx = blockIdx.x % nt, by = blockIdx.x / nt;
    int n0 = bx * 32, k0 = by * 32;
    int tx = threadIdx.x & 31, ty = threadIdx.x >> 5;
    #pragma unroll
    for (int i=0;i<4;i++)
        t[ty + i*8][tx] = in[(size_t)(k0 + ty + i*8) * N + n0 + tx];
    __syncthreads();
    #pragma unroll
    for (int i=0;i<4;i++)
        out[(size_t)(n0 + ty + i*8) * K + k0 + tx] = f2bf(t[tx][ty + i*8]);
}

// ---------------------------------------------------------------- key bias (mask -> additive f32)
__global__ __launch_bounds__(256) void kbias_kernel(const int* __restrict__ km, float* __restrict__ kb)
{
    int i = blockIdx.x * 256 + threadIdx.x;
    if (i >= 2 * KPAD) return;
    int b = i / KPAD, j = i - b * KPAD;
    float v;
    if (j < SEQ)       v = km[b*SEQ + j] ? 0.0f : -1e30f;
    else if (j == SEQ) v = 0.0f;     // zero-attn slot, mask bit = 1
    else               v = -1e30f;   // pad rows
    kb[i] = v;
}

// ---------------------------------------------------------------- bf16 GEMM 64x64 tile, BK=64
// A (M,K) bf16 rm, Bt (N,K) bf16 rm. 4 waves, each 32x32 (acc 2x2).
template<bool BF16OUT>
__global__ __launch_bounds__(256) void gemm64(
    const short* __restrict__ A, const short* __restrict__ Bt,
    void* __restrict__ Cv, int M, int N, int K)
{
    __shared__ short As[64*64];
    __shared__ short Bs[64*64];
    int tid = threadIdx.x;
    int w = tid >> 6, l = tid & 63;
    int lr = l & 15, lg = l >> 4;
    int nt = N >> 6;
    int tm = blockIdx.x / nt, tn = blockIdx.x - tm * nt;
    int wm = w >> 1, wn = w & 1;
    int srow = tid >> 3, sslot = tid & 7;

    f32x4 acc[2][2];
    #pragma unroll
    for (int m=0;m<2;m++)
        #pragma unroll
        for (int n=0;n<2;n++) acc[m][n] = (f32x4){0.f,0.f,0.f,0.f};

    for (int k0 = 0; k0 < K; k0 += 64) {
        #pragma unroll
        for (int i=0;i<2;i++){
            int row = i*32 + srow;
            int gslot = sslot ^ (row & 7);
            const short* ga = A  + (size_t)(tm*64 + row) * K + k0 + gslot*8;
            const short* gb = Bt + (size_t)(tn*64 + row) * K + k0 + gslot*8;
            short* la = As + (i*256 + w*64) * 8;
            short* lb = Bs + (i*256 + w*64) * 8;
            __builtin_amdgcn_global_load_lds((const __attribute__((address_space(1))) void*)ga,
                                             (__attribute__((address_space(3))) void*)la, 16, 0, 0);
            __builtin_amdgcn_global_load_lds((const __attribute__((address_space(1))) void*)gb,
                                             (__attribute__((address_space(3))) void*)lb, 16, 0, 0);
        }
        __syncthreads();
        #pragma unroll
        for (int s=0;s<2;s++){
            s16x8 af[2], bfr[2];
            #pragma unroll
            for (int m=0;m<2;m++){
                int row = wm*32 + m*16 + lr;
                int slot = (s*4 + lg) ^ (row & 7);
                af[m] = *(const s16x8*)(As + row*64 + slot*8);
            }
            #pragma unroll
            for (int n=0;n<2;n++){
                int row = wn*32 + n*16 + lr;
                int slot = (s*4 + lg) ^ (row & 7);
                bfr[n] = *(const s16x8*)(Bs + row*64 + slot*8);
            }
            #pragma unroll
            for (int m=0;m<2;m++)
                #pragma unroll
                for (int n=0;n<2;n++)
                    acc[m][n] = __builtin_amdgcn_mfma_f32_16x16x32_bf16(af[m], bfr[n], acc[m][n], 0, 0, 0);
        }
        __syncthreads();
    }

    #pragma unroll
    for (int n=0;n<2;n++){
        int col = tn*64 + wn*32 + n*16 + lr;
        #pragma unroll
        for (int m=0;m<2;m++){
            #pragma unroll
            for (int j=0;j<4;j++){
                int row = tm*64 + wm*32 + m*16 + lg*4 + j;
                float v = acc[m][n][j];
                if (BF16OUT) ((short*)Cv)[(size_t)row*N + col] = f2bf(v);
                else         ((float*)Cv)[(size_t)row*N + col] = v;
            }
        }
    }
}

// ---------------------------------------------------------------- gate GEMM (fused concat + sigmoid combine)
// A = concat(query, ap) f32 -> bf16 staged; B = gWT (512,1024); epilogue: out = q + g*q + (1-g)*ap
__global__ __launch_bounds__(256) void gate_gemm(
    const float* __restrict__ query, const float* __restrict__ ap,
    const short* __restrict__ gWT, const float* __restrict__ gB,
    float* __restrict__ out)
{
    __shared__ short As[64*64];
    __shared__ short Bs[64*64];
    int tid = threadIdx.x;
    int w = tid >> 6, l = tid & 63;
    int lr = l & 15, lg = l >> 4;
    int tm = blockIdx.x >> 3, tn = blockIdx.x & 7;
    int wm = w >> 1, wn = w & 1;
    int srow = tid >> 3, sslot = tid & 7;

    f32x4 acc[2][2];
    #pragma unroll
    for (int m=0;m<2;m++)
        #pragma unroll
        for (int n=0;n<2;n++) acc[m][n] = (f32x4){0.f,0.f,0.f,0.f};

    for (int k0 = 0; k0 < 1024; k0 += 64) {
        const float* src = (k0 < 512) ? query : ap;
        int csub = (k0 < 512) ? k0 : k0 - 512;
        #pragma unroll
        for (int i=0;i<2;i++){
            int row = i*32 + srow;
            // A: load f32, convert, swizzled LDS write
            const float* gp = src + (size_t)(tm*64 + row) * 512 + csub + sslot*8;
            f32x4 a0 = *(const f32x4*)gp;
            f32x4 a1 = *(const f32x4*)(gp + 4);
            s16x8 o;
            #pragma unroll
            for (int t=0;t<4;t++){ o[t] = f2bf(a0[t]); o[t+4] = f2bf(a1[t]); }
            int slot = sslot ^ (row & 7);
            *(s16x8*)(As + row*64 + slot*8) = o;
            // B: global_load_lds from gWT
            int gslot = sslot ^ (row & 7);
            const short* gb = gWT + (size_t)(tn*64 + row) * 1024 + k0 + gslot*8;
            short* lb = Bs + (i*256 + w*64) * 8;
            __builtin_amdgcn_global_load_lds((const __attribute__((address_space(1))) void*)gb,
                                             (__attribute__((address_space(3))) void*)lb, 16, 0, 0);
        }
        __syncthreads();
        #pragma unroll
        for (int s=0;s<2;s++){
            s16x8 af[2], bfr[2];
            #pragma unroll
            for (int m=0;m<2;m++){
                int row = wm*32 + m*16 + lr;
                int slot = (s*4 + lg) ^ (row & 7);
                af[m] = *(const s16x8*)(As + row*64 + slot*8);
            }
            #pragma unroll
            for (int n=0;n<2;n++){
                int row = wn*32 + n*16 + lr;
                int slot = (s*4 + lg) ^ (row & 7);
                bfr[n] = *(const s16x8*)(Bs + row*64 + slot*8);
            }
            #pragma unroll
            for (int m=0;m<2;m++)
                #pragma unroll
                for (int n=0;n<2;n++)
                    acc[m][n] = __builtin_amdgcn_mfma_f32_16x16x32_bf16(af[m], bfr[n], acc[m][n], 0, 0, 0);
        }
        __syncthreads();
    }

    #pragma unroll
    for (int n=0;n<2;n++){
        int col = tn*64 + wn*32 + n*16 + lr;
        float badd = gB[col];
        #pragma unroll
        for (int m=0;m<2;m++){
            #pragma unroll
            for (int j=0;j<4;j++){
                int row = tm*64 + wm*32 + m*16 + lg*4 + j;
                size_t idx = (size_t)row*512 + col;
                float g = 1.0f / (1.0f + __expf(-(acc[m][n][j] + badd)));
                float q = query[idx], a = ap[idx];
                out[idx] = q + g*q + (1.0f - g)*a;
            }
        }
    }
}

// ---------------------------------------------------------------- vh -> vhT[b][h][64][KPAD]
__global__ __launch_bounds__(256) void transpose_v(
    const short* __restrict__ vh, short* __restrict__ vhT)
{
    __shared__ short t[64][72];
    int tid = threadIdx.x, bid = blockIdx.x;
    int kt = bid % 33; int hh = (bid / 33) & 7; int b = bid / (33*8);
    int k0 = kt * 64;
    int rr = tid >> 3, c8 = (tid & 7) * 8;
    #pragma unroll
    for (int p=0;p<2;p++){
        int kr = p*32 + rr;
        int gk = k0 + kr;
        s16x8 v = {0,0,0,0,0,0,0,0};
        if (gk < KPAD) v = *(const s16x8*)(vh + (size_t)(b*KPAD + gk)*DMODEL + hh*64 + c8);
        *(s16x8*)&t[kr][c8] = v;
    }
    __syncthreads();
    #pragma unroll
    for (int p=0;p<2;p++){
        int dr = p*32 + rr;
        if (k0 + c8 < KPAD){
            s16x8 o;
            #pragma unroll
            for (int j2=0;j2<8;j2++) o[j2] = t[c8+j2][dr];
            *(s16x8*)(vhT + ((size_t)(b*8 + hh)*64 + dr)*KPAD + k0 + c8) = o;
        }
    }
}

// ---------------------------------------------------------------- flash attention, split-KV 2-way
// wave wid: [half:1][b:1][h:3][qtile:7]. half0: keys 0..1023 (16 chunks of 64);
// half1: keys 1024..2047 (16 chunks) + tail 2048..2079 (32 keys).
// Outputs: On[half][r][64] = O/l (bf16), ml[half][r] = (m, l) f32.
__global__ __launch_bounds__(256, 4) void flash_kernel(
    const short* __restrict__ qh, const short* __restrict__ kh,
    const short* __restrict__ vhT, const float* __restrict__ kbias,
    short* __restrict__ On, float* __restrict__ ml)
{
    __shared__ short plds[4][16*72];
    int tid = threadIdx.x;
    int w = tid >> 6, l = tid & 63;
    int wid = blockIdx.x * 4 + w;
    int half = wid >> 11;
    int b = (wid >> 10) & 1;
    int h = (wid >> 7) & 7;
    int q0 = (wid & 127) << 4;
    int cl = l & 15, rg = l >> 4;

    const short* qp = qh + ((size_t)(b*SEQ + q0 + cl))*DMODEL + h*64 + rg*8;
    s16x8 qf0 = *(const s16x8*)qp;
    s16x8 qf1 = *(const s16x8*)(qp + 32);

    f32x4 O[4];
    float mrow[4], lsum[4];
    #pragma unroll
    for (int n=0;n<4;n++) O[n] = (f32x4){0.f,0.f,0.f,0.f};
    #pragma unroll
    for (int j=0;j<4;j++){ mrow[j] = -1e30f; lsum[j] = 0.f; }

    const short* khb = kh + (size_t)b*KPAD*DMODEL + h*64;
    const short* vtb = vhT + (size_t)(b*8 + h)*64*KPAD;
    const float* kbb = kbias + b*KPAD;
    short* pl = plds[w];

    int kc0 = half ? 16 : 0;
    for (int kc = kc0; kc < kc0 + 16; ++kc) {
        int k0 = kc * 64;
        float sv[4][4];
        #pragma unroll
        for (int nh=0; nh<4; ++nh) {
            const short* kp = khb + (size_t)(k0 + nh*16 + cl)*DMODEL + rg*8;
            s16x8 ka = *(const s16x8*)kp;
            s16x8 kb2 = *(const s16x8*)(kp + 32);
            f32x4 z = (f32x4){0.f,0.f,0.f,0.f};
            z = __builtin_amdgcn_mfma_f32_16x16x32_bf16(qf0, ka,  z, 0, 0, 0);
            z = __builtin_amdgcn_mfma_f32_16x16x32_bf16(qf1, kb2, z, 0, 0, 0);
            float bias = kbb[k0 + nh*16 + cl];
            #pragma unroll
            for (int j=0;j<4;j++) sv[nh][j] = fmaf(z[j], 0.125f, bias);
        }
        float ml4[4];
        #pragma unroll
        for (int j=0;j<4;j++)
            ml4[j] = fmaxf(fmaxf(sv[0][j], sv[1][j]), fmaxf(sv[2][j], sv[3][j]));
        #pragma unroll
        for (int off=1; off<16; off<<=1){
            #pragma unroll
            for (int j=0;j<4;j++) ml4[j] = fmaxf(ml4[j], __shfl_xor(ml4[j], off));
        }
        // defer-max: only rescale when chunk max exceeds running max by > 8
        bool need = (ml4[0] > mrow[0]+8.f) || (ml4[1] > mrow[1]+8.f) ||
                    (ml4[2] > mrow[2]+8.f) || (ml4[3] > mrow[3]+8.f);
        if (__any(need)) {
            #pragma unroll
            for (int j=0;j<4;j++){
                float mn = fmaxf(mrow[j], ml4[j]);
                float sc = __expf(mrow[j] - mn);
                mrow[j] = mn; lsum[j] *= sc;
                #pragma unroll
                for (int n=0;n<4;n++) O[n][j] *= sc;
            }
        }
        float ps[4] = {0.f,0.f,0.f,0.f};
        #pragma unroll
        for (int nh=0; nh<4; ++nh){
            #pragma unroll
            for (int j=0;j<4;j++){
                float p = __expf(sv[nh][j] - mrow[j]);
                ps[j] += p;
                pl[(rg*4 + j)*72 + nh*16 + cl] = f2bf(p);
            }
        }
        #pragma unroll
        for (int off=1; off<16; off<<=1){
            #pragma unroll
            for (int j=0;j<4;j++) ps[j] += __shfl_xor(ps[j], off);
        }
        #pragma unroll
        for (int j=0;j<4;j++) lsum[j] += ps[j];

        s16x8 pa0 = *(const s16x8*)(pl + cl*72 + rg*8);
        s16x8 pa1 = *(const s16x8*)(pl + cl*72 + 32 + rg*8);
        __builtin_amdgcn_s_setprio(1);
        #pragma unroll
        for (int n=0;n<4;n++){
            s16x8 vf0 = *(const s16x8*)(vtb + (size_t)(n*16 + cl)*KPAD + k0 + rg*8);
            s16x8 vf1 = *(const s16x8*)(vtb + (size_t)(n*16 + cl)*KPAD + k0 + 32 + rg*8);
            O[n] = __builtin_amdgcn_mfma_f32_16x16x32_bf16(pa0, vf0, O[n], 0, 0, 0);
            O[n] = __builtin_amdgcn_mfma_f32_16x16x32_bf16(pa1, vf1, O[n], 0, 0, 0);
        }
        __builtin_amdgcn_s_setprio(0);
    }

    if (half) {  // tail: keys 2048..2079 (32 keys, 2 nh groups)
        int k0 = 2048;
        float sv[2][4];
        #pragma unroll
        for (int nh=0; nh<2; ++nh) {
            const short* kp = khb + (size_t)(k0 + nh*16 + cl)*DMODEL + rg*8;
            s16x8 ka = *(const s16x8*)kp;
            s16x8 kb2 = *(const s16x8*)(kp + 32);
            f32x4 z = (f32x4){0.f,0.f,0.f,0.f};
            z = __builtin_amdgcn_mfma_f32_16x16x32_bf16(qf0, ka,  z, 0, 0, 0);
            z = __builtin_amdgcn_mfma_f32_16x16x32_bf16(qf1, kb2, z, 0, 0, 0);
            float bias = kbb[k0 + nh*16 + cl];
            #pragma unroll
            for (int j=0;j<4;j++) sv[nh][j] = fmaf(z[j], 0.125f, bias);
        }
        float ml4[4];
        #pragma unroll
        for (int j=0;j<4;j++) ml4[j] = fmaxf(sv[0][j], sv[1][j]);
        #pragma unroll
        for (int off=1; off<16; off<<=1){
            #pragma unroll
            for (int j=0;j<4;j++) ml4[j] = fmaxf(ml4[j], __shfl_xor(ml4[j], off));
        }
        bool need = (ml4[0] > mrow[0]+8.f) || (ml4[1] > mrow[1]+8.f) ||
                    (ml4[2] > mrow[2]+8.f) || (ml4[3] > mrow[3]+8.f);
        if (__any(need)) {
            #pragma unroll
            for (int j=0;j<4;j++){
                float mn = fmaxf(mrow[j], ml4[j]);
                float sc = __expf(mrow[j] - mn);
                mrow[j] = mn; lsum[j] *= sc;
                #pragma unroll
                for (int n=0;n<4;n++) O[n][j] *= sc;
            }
        }
        float ps[4] = {0.f,0.f,0.f,0.f};
        #pragma unroll
        for (int nh=0; nh<2; ++nh){
            #pragma unroll
            for (int j=0;j<4;j++){
                float p = __expf(sv[nh][j] - mrow[j]);
                ps[j] += p;
                pl[(rg*4 + j)*72 + nh*16 + cl] = f2bf(p);
            }
        }
        #pragma unroll
        for (int off=1; off<16; off<<=1){
            #pragma unroll
            for (int j=0;j<4;j++) ps[j] += __shfl_xor(ps[j], off);
        }
        #pragma unroll
        for (int j=0;j<4;j++) lsum[j] += ps[j];

        s16x8 pa0 = *(const s16x8*)(pl + cl*72 + rg*8);
        __builtin_amdgcn_s_setprio(1);
        #pragma unroll
        for (int n=0;n<4;n++){
            s16x8 vf0 = *(const s16x8*)(vtb + (size_t)(n*16 + cl)*KPAD + k0 + rg*8);
            O[n] = __builtin_amdgcn_mfma_f32_16x16x32_bf16(pa0, vf0, O[n], 0, 0, 0);
        }
        __builtin_amdgcn_s_setprio(0);
    }

    // store normalized partial + (m, l)
    int rbase = ((b*8 + h) << 11) + q0;
    #pragma unroll
    for (int j=0;j<4;j++){
        int r = rbase + rg*4 + j;
        float invl = 1.0f / lsum[j];
        #pragma unroll
        for (int n=0;n<4;n++)
            On[((size_t)half*NROWS + r)*64 + n*16 + cl] = f2bf(O[n][j] * invl);
        if (cl == 0){
            ml[((size_t)half*NROWS + r)*2    ] = mrow[j];
            ml[((size_t)half*NROWS + r)*2 + 1] = lsum[j];
        }
    }
}

// ---------------------------------------------------------------- merge split-KV partials -> av bf16
__global__ __launch_bounds__(256) void merge_kernel(
    const short* __restrict__ On, const float* __restrict__ ml,
    const int* __restrict__ qmask, short* __restrict__ av)
{
    int tid = threadIdx.x;
    int r = blockIdx.x * 32 + (tid >> 3);
    int d8 = (tid & 7) * 8;
    float m1 = ml[(size_t)r*2], l1 = ml[(size_t)r*2 + 1];
    float m2 = ml[((size_t)NROWS + r)*2], l2 = ml[((size_t)NROWS + r)*2 + 1];
    float m = fmaxf(m1, m2);
    float w1 = l1 * __expf(m1 - m), w2 = l2 * __expf(m2 - m);
    int qrow = r & 2047, bh = r >> 11, h = bh & 7, b = bh >> 3;
    int qm = qmask[b*SEQ + qrow];
    float inv = qm ? 1.0f / (w1 + w2) : 0.0f;
    w1 *= inv; w2 *= inv;
    s16x8 o1 = *(const s16x8*)(On + (size_t)r*64 + d8);
    s16x8 o2 = *(const s16x8*)(On + ((size_t)NROWS + r)*64 + d8);
    s16x8 o;
    #pragma unroll
    for (int e=0;e<8;e++) o[e] = f2bf(w1 * bf2f(o1[e]) + w2 * bf2f(o2[e]));
    *(s16x8*)(av + ((size_t)(b*SEQ + qrow))*DMODEL + h*64 + d8) = o;
}

// ---------------------------------------------------------------- launch
extern "C" void kernel_launch(void* const* d_in, const int* in_sizes, int n_in,
                              void* d_out, int out_size, void* d_ws, size_t ws_size,
                              hipStream_t stream)
{
    const float* query = (const float*)d_in[0];
    const float* key   = (const float*)d_in[1];
    const float* value = (const float*)d_in[2];
    const float* Wq    = (const float*)d_in[3];
    const float* Wk    = (const float*)d_in[4];
    const float* Wv    = (const float*)d_in[5];
    const float* Wo    = (const float*)d_in[6];
    const float* gW    = (const float*)d_in[7];
    const float* gB    = (const float*)d_in[8];
    const float* qg    = (const float*)d_in[9];
    const float* qb    = (const float*)d_in[10];
    const float* kg    = (const float*)d_in[11];
    const float* kb    = (const float*)d_in[12];
    const float* vg    = (const float*)d_in[13];
    const float* vb    = (const float*)d_in[14];
    const int* qmask   = (const int*)d_in[15];
    const int* kmask   = (const int*)d_in[16];
    float* out = (float*)d_out;
    char* ws = (char*)d_ws;

    if (ws_size < WS_NEEDED) return;

    short* qn  = (short*)(ws + OFF_QN);
    short* kn  = (short*)(ws + OFF_KN);
    short* vn  = (short*)(ws + OFF_VN);
    short* qh  = (short*)(ws + OFF_QH);
    short* khp = (short*)(ws + OFF_KH);
    short* vhp = (short*)(ws + OFF_VH);
    short* vhT = (short*)(ws + OFF_VHT);
    short* av  = (short*)(ws + OFF_AV);
    short* WqT = (short*)(ws + OFF_WQT);
    short* WkT = (short*)(ws + OFF_WKT);
    short* WvT = (short*)(ws + OFF_WVT);
    short* WoT = (short*)(ws + OFF_WOT);
    short* gWT = (short*)(ws + OFF_GWT);
    short* On  = (short*)(ws + OFF_ON);
    float* mlp = (float*)(ws + OFF_ML);
    float* kbp = (float*)(ws + OFF_KB);
    float* ap  = (float*)(ws + OFF_AP);

    // 1. layernorm + cast (K/V padded to 2080 rows/batch)
    ln_kernel<<<1024, 256, 0, stream>>>(query, qg, qb, qn, SEQ, SEQ, 2);
    ln_kernel<<<1040, 256, 0, stream>>>(key,   kg, kb, kn, SEQ, KPAD, 2);
    ln_kernel<<<1040, 256, 0, stream>>>(value, vg, vb, vn, SEQ, KPAD, 2);

    // 2. weights -> bf16 transposed (N,K), coalesced
    wt_cast_t<<<256, 256, 0, stream>>>(Wq, WqT, 512, 512);
    wt_cast_t<<<256, 256, 0, stream>>>(Wk, WkT, 512, 512);
    wt_cast_t<<<256, 256, 0, stream>>>(Wv, WvT, 512, 512);
    wt_cast_t<<<256, 256, 0, stream>>>(Wo, WoT, 512, 512);
    wt_cast_t<<<512, 256, 0, stream>>>(gW, gWT, 1024, 512);

    // 3. projections (bf16 out), 64x64 tiles
    gemm64<true><<<512, 256, 0, stream>>>(qn, WqT, qh,  4096, 512, 512);
    gemm64<true><<<520, 256, 0, stream>>>(kn, WkT, khp, 4160, 512, 512);
    gemm64<true><<<520, 256, 0, stream>>>(vn, WvT, vhp, 4160, 512, 512);

    // 4. key bias (after v-proj: lives in dead vn region) + V transpose
    kbias_kernel<<<17, 256, 0, stream>>>(kmask, kbp);
    transpose_v<<<528, 256, 0, stream>>>(vhp, vhT);

    // 5. flash attention, split-KV 2-way
    flash_kernel<<<1024, 256, 0, stream>>>(qh, khp, vhT, kbp, On, mlp);
    merge_kernel<<<1024, 256, 0, stream>>>(On, mlp, qmask, av);

    // 6. output projection (f32 out)
    gemm64<false><<<512, 256, 0, stream>>>(av, WoT, ap, 4096, 512, 512);

    // 7. gate GEMM fused: concat-stage + sigmoid + residual
    gate_gemm<<<512, 256, 0, stream>>>(query, ap, gWT, gB, out);

    (void)in_sizes; (void)n_in; (void)out_size;
}